// Round 15
// baseline (481.399 us; speedup 1.0000x reference)
//
#include <hip/hip_runtime.h>

// Problem constants
#define BT_TOTAL (32 * 1024)   // B*T = 32768
#define DIM 512                // D
#define NG 8                   // G groups
#define NK 256                 // K codes per group
#define GD 64                  // group dim
#define QB 128                 // queries per block (x2 k-halves = 256 threads)

#define XQ_ELEMS (BT_TOTAL * DIM)          // 16777216
#define LOSS_OFF XQ_ELEMS                  // 16777216
#define IDX_OFF (XQ_ELEMS + 1)             // 16777217

// ---------------------------------------------------------------------------
// Prep: c_sq[g][k] = sum_d cb[g][k][d]^2 (canonical stride-4 order), zero loss
// ---------------------------------------------------------------------------
__global__ void pq_prep(const float* __restrict__ cb,
                        float* __restrict__ csq,
                        float* __restrict__ loss_slot) {
    int i = blockIdx.x * 256 + threadIdx.x;  // 0 .. 2047
    if (i == 0) *loss_slot = 0.0f;
    if (i < NG * NK) {
        const float* row = cb + (size_t)i * GD;
        float a0 = 0.f, a1 = 0.f, a2 = 0.f, a3 = 0.f;
#pragma unroll
        for (int d = 0; d < GD; d += 4) {
            a0 = fmaf(row[d + 0], row[d + 0], a0);
            a1 = fmaf(row[d + 1], row[d + 1], a1);
            a2 = fmaf(row[d + 2], row[d + 2], a2);
            a3 = fmaf(row[d + 3], row[d + 3], a3);
        }
        csq[i] = (a0 + a1) + (a2 + a3);
    }
}

// ---------------------------------------------------------------------------
// Main: 256 threads = 128 queries x 2 k-halves (r10 geometry). Code rows
// stream through the VECTOR memory path: a 32-bit per-k byte offset is
// laundered through a single-dword "+v" asm tie (compile-proven form), so
// the backend CANNOT re-scalarize the loads -> global_load_dwordx4 with
// in-order vmcnt, which the compiler software-pipelines across iterations
// (explicit rc/rn double buffer). lgkmcnt(0) drains are GONE from the k-loop.
// Per-query numerics bit-match the absmax-0.0 rounds (dims-ascending,
// d0..d3 = dim%4 chains, same dist expression, strict-< ascending argmin).
// ---------------------------------------------------------------------------
__global__ __launch_bounds__(256)
void pq_main(const float* __restrict__ x,
             const float* __restrict__ cb,
             const float* __restrict__ csq,
             float* __restrict__ out) {
    const int g = blockIdx.y;
    const int t = threadIdx.x;
    const int kh = __builtin_amdgcn_readfirstlane(t >> 7);  // wave-uniform 0/1
    const int ql = t & (QB - 1);
    const int q0 = blockIdx.x * QB;
    const int bt = q0 + ql;

    __shared__ float m_d[QB];
    __shared__ int   m_i[QB];
    __shared__ float wsum[4];

    const float* cbg = cb + (size_t)g * NK * GD;
    const float* csqg = csq + g * NK;

    // x row -> 64 scalar VGPR values (vectorized loads)
    const float* xrow = x + (size_t)bt * DIM + g * GD;
    float xr[64];
#pragma unroll
    for (int i = 0; i < 16; ++i) {
        float4 v = ((const float4*)xrow)[i];
        xr[i * 4 + 0] = v.x;
        xr[i * 4 + 1] = v.y;
        xr[i * 4 + 2] = v.z;
        xr[i * 4 + 3] = v.w;
    }

    // x_sq, canonical stride-4 pattern (bit-matches rounds 1-14)
    float a0 = 0.f, a1 = 0.f, a2 = 0.f, a3 = 0.f;
#pragma unroll
    for (int i = 0; i < 16; ++i) {
        a0 = fmaf(xr[i * 4 + 0], xr[i * 4 + 0], a0);
        a1 = fmaf(xr[i * 4 + 1], xr[i * 4 + 1], a1);
        a2 = fmaf(xr[i * 4 + 2], xr[i * 4 + 2], a2);
        a3 = fmaf(xr[i * 4 + 3], xr[i * 4 + 3], a3);
    }
    const float x_sq = (a0 + a1) + (a2 + a3);

    const int kbase = kh << 7;  // 0 or 128, wave-uniform
    float best = 3.402823466e38f;
    int bi = kbase;

    // Laundered 32-bit byte offset of the current row within the group's
    // codebook: single-dword "+v" tie -> backend must treat it as divergent
    // -> vector global_load path (in-order vmcnt, compiler-pipelined).
    unsigned off0 = (unsigned)kbase * (GD * 4);
    asm("" : "+v"(off0));

    // prologue: load row kbase into rc
    float4 rc[16];
    {
        const float4* p = (const float4*)((const char*)cbg + off0);
#pragma unroll
        for (int j = 0; j < 16; ++j) rc[j] = p[j];
    }

#pragma unroll 1
    for (int kk = 0; kk < NK / 2; ++kk) {
        const int k = kbase + kk;

        // issue next row's (laundered) vector loads before consuming rc
        unsigned offn = (unsigned)(kbase + ((kk + 1) & (NK / 2 - 1))) * (GD * 4);
        asm("" : "+v"(offn));
        const float4* pn = (const float4*)((const char*)cbg + offn);
        float4 rn[16];
#pragma unroll
        for (int j = 0; j < 16; ++j) rn[j] = pn[j];

        const float cs = csqg[k];   // scalar path, 64B line covers 16 k's

        // dot, dims ascending, accumulator = dim%4 (bit-matches r1/r2/r10)
        float d0 = 0.f, d1 = 0.f, d2 = 0.f, d3 = 0.f;
#pragma unroll
        for (int i = 0; i < 16; ++i) {
            d0 = fmaf(rc[i].x, xr[i * 4 + 0], d0);
            d1 = fmaf(rc[i].y, xr[i * 4 + 1], d1);
            d2 = fmaf(rc[i].z, xr[i * 4 + 2], d2);
            d3 = fmaf(rc[i].w, xr[i * 4 + 3], d3);
        }
        float dot = (d0 + d1) + (d2 + d3);
        float dist = (x_sq + cs) - 2.0f * dot;
        if (dist < best) { best = dist; bi = k; }

        // rotate buffers (register renaming)
#pragma unroll
        for (int j = 0; j < 16; ++j) rc[j] = rn[j];
    }

    // merge the two halves: prefer the lower half on exact ties
    if (kh == 1) { m_d[ql] = best; m_i[ql] = bi; }
    __syncthreads();
    if (kh == 0) {
        float dh = m_d[ql];
        int ih = m_i[ql];
        if (dh < best) { best = dh; bi = ih; }
        m_i[ql] = bi;  // final winner for the epilogue
        out[IDX_OFF + (size_t)bt * NG + g] = (float)bi;
    }
    __syncthreads();

    // ---- epilogue: coalesced x_q writes + loss partial (r10 verbatim) ----
    const int r_off = t >> 4;   // 0..15
    const int c4i = t & 15;     // float4 column
    float s0 = 0.f, s1 = 0.f, s2 = 0.f, s3 = 0.f;
#pragma unroll
    for (int p = 0; p < 8; ++p) {
        const int r = p * 16 + r_off;
        const int code = m_i[r];
        const size_t base = (size_t)(q0 + r) * DIM + g * GD + c4i * 4;
        float4 x4 = *(const float4*)(x + base);
        float4 q4 = *(const float4*)(cbg + (size_t)code * GD + c4i * 4);
        float dx = q4.x - x4.x;
        float dy = q4.y - x4.y;
        float dz = q4.z - x4.z;
        float dw = q4.w - x4.w;
        float4 o;
        o.x = x4.x + dx;
        o.y = x4.y + dy;
        o.z = x4.z + dz;
        o.w = x4.w + dw;
        *(float4*)(out + base) = o;
        s0 = fmaf(dx, dx, s0);
        s1 = fmaf(dy, dy, s1);
        s2 = fmaf(dz, dz, s2);
        s3 = fmaf(dw, dw, s3);
    }
    float part = (s0 + s1) + (s2 + s3);

    // wave reduce (64 lanes)
#pragma unroll
    for (int off = 32; off > 0; off >>= 1) part += __shfl_down(part, off);

    const int lane = t & 63;
    const int wid = t >> 6;
    if (lane == 0) wsum[wid] = part;
    __syncthreads();
    if (t == 0) {
        float bs = (wsum[0] + wsum[1]) + (wsum[2] + wsum[3]);
        // losses = 2 * sum_g mean_{B,T,gd}; divisor = 32768*64 = 2097152
        atomicAdd(out + LOSS_OFF, bs * (2.0f / 2097152.0f));
    }
}

extern "C" void kernel_launch(void* const* d_in, const int* in_sizes, int n_in,
                              void* d_out, int out_size, void* d_ws, size_t ws_size,
                              hipStream_t stream) {
    const float* x = (const float*)d_in[0];
    const float* cb = (const float*)d_in[1];
    float* out = (float*)d_out;
    float* csq = (float*)d_ws;  // 2048 floats = 8 KB scratch

    pq_prep<<<dim3(8), dim3(256), 0, stream>>>(cb, csq, out + LOSS_OFF);

    dim3 grid(BT_TOTAL / QB, NG);   // (256, 8) = 2048 blocks, 8192 waves
    pq_main<<<grid, dim3(256), 0, stream>>>(x, cb, csq, out);
}

// Round 16
// 203.401 us; speedup vs baseline: 2.3668x; 2.3668x over previous
//
#include <hip/hip_runtime.h>
#include <hip/hip_bf16.h>

// Problem constants
#define BT_TOTAL (32 * 1024)   // B*T
#define DIM 512
#define NG 8
#define NK 256
#define GD 64
#define QB 64                  // queries per block
#define ROWS 72                // LDS row stride in bf16 elems (64 + 8 pad = 144 B)

#define XQ_ELEMS (BT_TOTAL * DIM)
#define LOSS_OFF XQ_ELEMS
#define IDX_OFF (XQ_ELEMS + 1)

typedef short s16x8 __attribute__((ext_vector_type(8)));
typedef float f32x4 __attribute__((ext_vector_type(4)));

__device__ __forceinline__ unsigned short f2bf(float f) {
    __hip_bfloat16 h = __float2bfloat16(f);
    union { __hip_bfloat16 h; unsigned short u; } cv;
    cv.h = h;
    return cv.u;
}

__global__ void pq_zero(float* loss_slot) {
    if (threadIdx.x == 0 && blockIdx.x == 0) *loss_slot = 0.0f;
}

// ---------------------------------------------------------------------------
// MFMA bf16 screen + guaranteed-window exact fp32 rescore.
// Block: 256 threads (4 waves) = 64 queries x 1 group; waves split the 256
// codes 4-way (64 each). Screen dist_c = csq - 2*dot_bf16 (x_sq drops out of
// argmin). Candidate window delta_row >= 2*eps_row (deterministic bf16 error
// bound from sum|x|) guarantees the true fp32 argmin is rescored with the
// canonical absmax-0.0 numerics.
// ---------------------------------------------------------------------------
__global__ __launch_bounds__(256, 2)
void pq_main(const float* __restrict__ x,
             const float* __restrict__ cb,
             float* __restrict__ out) {
    const int g = blockIdx.y;
    const int t = threadIdx.x;
    const int lane = t & 63;
    const int wid = __builtin_amdgcn_readfirstlane(t >> 6);
    const int q0 = blockIdx.x * QB;

    __shared__ unsigned short xh[QB * ROWS];      // 9216 B
    __shared__ unsigned short ch[NK * ROWS];      // 36864 B
    __shared__ float csq_l[NK];                   // 1024 B (canonical, bit = prep)
    __shared__ float absrow[QB];
    __shared__ float wredv[4][QB];
    __shared__ int   wredi[4][QB];
    __shared__ float sminl[QB];
    __shared__ int   swinl[QB];
    __shared__ int   ccount[QB];
    __shared__ unsigned short cand[QB][8];
    __shared__ int   m_i[QB];
    __shared__ float wsum[4];

    if (t < QB) { absrow[t] = 0.f; ccount[t] = 0; }
    __syncthreads();

    // ---- stage x -> bf16 LDS (+ per-row sum|x| for the error bound) ----
    {
        const int row = t >> 2, seg = t & 3;  // 4 threads/row, 16 elems each
        const float* xg = x + (size_t)(q0 + row) * DIM + g * GD + seg * 16;
        float tmp[16];
        float s = 0.f;
#pragma unroll
        for (int i = 0; i < 4; ++i) {
            float4 v = ((const float4*)xg)[i];
            tmp[i * 4 + 0] = v.x; tmp[i * 4 + 1] = v.y;
            tmp[i * 4 + 2] = v.z; tmp[i * 4 + 3] = v.w;
            s += fabsf(v.x) + fabsf(v.y) + fabsf(v.z) + fabsf(v.w);
        }
        s16x8 w0, w1;
#pragma unroll
        for (int j = 0; j < 8; ++j) {
            w0[j] = (short)f2bf(tmp[j]);
            w1[j] = (short)f2bf(tmp[8 + j]);
        }
        *(s16x8*)&xh[row * ROWS + seg * 16]     = w0;
        *(s16x8*)&xh[row * ROWS + seg * 16 + 8] = w1;
        atomicAdd(&absrow[row], s);
    }
    // ---- stage cb -> bf16 LDS + canonical csq (bit-matches prep order) ----
    {
        const float* cr = cb + ((size_t)g * NK + t) * GD;
        float a0 = 0.f, a1 = 0.f, a2 = 0.f, a3 = 0.f;
#pragma unroll
        for (int i = 0; i < 8; ++i) {
            float4 vA = ((const float4*)cr)[i * 2 + 0];
            float4 vB = ((const float4*)cr)[i * 2 + 1];
            a0 = fmaf(vA.x, vA.x, a0); a1 = fmaf(vA.y, vA.y, a1);
            a2 = fmaf(vA.z, vA.z, a2); a3 = fmaf(vA.w, vA.w, a3);
            a0 = fmaf(vB.x, vB.x, a0); a1 = fmaf(vB.y, vB.y, a1);
            a2 = fmaf(vB.z, vB.z, a2); a3 = fmaf(vB.w, vB.w, a3);
            s16x8 w;
            w[0] = (short)f2bf(vA.x); w[1] = (short)f2bf(vA.y);
            w[2] = (short)f2bf(vA.z); w[3] = (short)f2bf(vA.w);
            w[4] = (short)f2bf(vB.x); w[5] = (short)f2bf(vB.y);
            w[6] = (short)f2bf(vB.z); w[7] = (short)f2bf(vB.w);
            *(s16x8*)&ch[t * ROWS + i * 8] = w;
        }
        csq_l[t] = (a0 + a1) + (a2 + a3);
    }
    __syncthreads();

    // ---- fragments + MFMA screen ----
    const int lr = lane & 15, lh = lane >> 4;
    const int nb = wid * 64;                 // this wave's code range
    s16x8 af[4][2], bq[4][2];
#pragma unroll
    for (int m = 0; m < 4; ++m)
#pragma unroll
        for (int s = 0; s < 2; ++s)
            af[m][s] = *(const s16x8*)&xh[(m * 16 + lr) * ROWS + s * 32 + lh * 8];
#pragma unroll
    for (int n = 0; n < 4; ++n)
#pragma unroll
        for (int s = 0; s < 2; ++s)
            bq[n][s] = *(const s16x8*)&ch[(nb + n * 16 + lr) * ROWS + s * 32 + lh * 8];
    float csr[4];
#pragma unroll
    for (int n = 0; n < 4; ++n) csr[n] = csq_l[nb + n * 16 + lr];

    f32x4 acc[4][4];
#pragma unroll
    for (int m = 0; m < 4; ++m)
#pragma unroll
        for (int n = 0; n < 4; ++n) {
            f32x4 z = {0.f, 0.f, 0.f, 0.f};
            z = __builtin_amdgcn_mfma_f32_16x16x32_bf16(af[m][0], bq[n][0], z, 0, 0, 0);
            z = __builtin_amdgcn_mfma_f32_16x16x32_bf16(af[m][1], bq[n][1], z, 0, 0, 0);
            acc[m][n] = z;
        }

    // ---- per-lane fold (k ascending, strict <) ----
    float mv[4][4]; int mi[4][4];
#pragma unroll
    for (int m = 0; m < 4; ++m)
#pragma unroll
        for (int r = 0; r < 4; ++r) { mv[m][r] = 3.402823466e38f; mi[m][r] = 0; }
#pragma unroll
    for (int m = 0; m < 4; ++m)
#pragma unroll
        for (int n = 0; n < 4; ++n) {
            const int k = nb + n * 16 + lr;
#pragma unroll
            for (int r = 0; r < 4; ++r) {
                float dc = fmaf(-2.f, acc[m][n][r], csr[n]);
                if (dc < mv[m][r]) { mv[m][r] = dc; mi[m][r] = k; }
            }
        }
    // 16-lane lexicographic reduce (cols of each tile-row live in 16 consecutive lanes)
#pragma unroll
    for (int w = 1; w < 16; w <<= 1) {
#pragma unroll
        for (int m = 0; m < 4; ++m)
#pragma unroll
            for (int r = 0; r < 4; ++r) {
                float ov = __shfl_xor(mv[m][r], w);
                int   oi = __shfl_xor(mi[m][r], w);
                if (ov < mv[m][r] || (ov == mv[m][r] && oi < mi[m][r])) {
                    mv[m][r] = ov; mi[m][r] = oi;
                }
            }
    }
    if (lr == 0) {
#pragma unroll
        for (int m = 0; m < 4; ++m)
#pragma unroll
            for (int r = 0; r < 4; ++r) {
                const int row = m * 16 + lh * 4 + r;
                wredv[wid][row] = mv[m][r];
                wredi[wid][row] = mi[m][r];
            }
    }
    __syncthreads();

    // ---- cross-wave merge (waves ascend in k -> lexicographic is first-min) ----
    if (t < QB) {
        float v = wredv[0][t]; int i0 = wredi[0][t];
#pragma unroll
        for (int w = 1; w < 4; ++w) {
            float ov = wredv[w][t]; int oi = wredi[w][t];
            if (ov < v || (ov == v && oi < i0)) { v = ov; i0 = oi; }
        }
        sminl[t] = v; swinl[t] = i0;
    }
    __syncthreads();

    // ---- flag candidates within the guaranteed window ----
#pragma unroll
    for (int m = 0; m < 4; ++m)
#pragma unroll
        for (int r = 0; r < 4; ++r) {
            const int row = m * 16 + lh * 4 + r;
            const float thr = sminl[row] + (absrow[row] * 6.2e-5f + 1.5e-3f);
#pragma unroll
            for (int n = 0; n < 4; ++n) {
                float dc = fmaf(-2.f, acc[m][n][r], csr[n]);
                if (dc <= thr) {
                    int slot = atomicAdd(&ccount[row], 1);
                    if (slot < 8) cand[row][slot] = (unsigned short)(nb + n * 16 + lr);
                }
            }
        }
    __syncthreads();

    // ---- exact fp32 rescore (canonical absmax-0.0 numerics) ----
    if (t < QB) {
        const int nc = ccount[t];
        int bi;
        if (nc <= 1) {
            bi = swinl[t];
        } else {
            const float* xrow = x + (size_t)(q0 + t) * DIM + g * GD;
            float xr[64];
#pragma unroll
            for (int i = 0; i < 16; ++i) {
                float4 v = ((const float4*)xrow)[i];
                xr[i * 4 + 0] = v.x; xr[i * 4 + 1] = v.y;
                xr[i * 4 + 2] = v.z; xr[i * 4 + 3] = v.w;
            }
            float a0 = 0.f, a1 = 0.f, a2 = 0.f, a3 = 0.f;
#pragma unroll
            for (int i = 0; i < 16; ++i) {
                a0 = fmaf(xr[i * 4 + 0], xr[i * 4 + 0], a0);
                a1 = fmaf(xr[i * 4 + 1], xr[i * 4 + 1], a1);
                a2 = fmaf(xr[i * 4 + 2], xr[i * 4 + 2], a2);
                a3 = fmaf(xr[i * 4 + 3], xr[i * 4 + 3], a3);
            }
            const float x_sq = (a0 + a1) + (a2 + a3);

            const bool full = nc > 8;           // astronomically rare; exact fallback
            unsigned short ks[8];
            const int mcnt = full ? 0 : nc;
            for (int i = 0; i < mcnt; ++i) ks[i] = cand[t][i];
            for (int i = 1; i < mcnt; ++i) {    // ascending k -> first-min scan
                unsigned short key = ks[i];
                int j = i - 1;
                while (j >= 0 && ks[j] > key) { ks[j + 1] = ks[j]; --j; }
                ks[j + 1] = key;
            }
            float best = 3.402823466e38f; bi = 0;
            const int total = full ? NK : mcnt;
            for (int ii = 0; ii < total; ++ii) {
                const int k = full ? ii : (int)ks[ii];
                const float* ckr = cb + ((size_t)g * NK + k) * GD;
                float d0 = 0.f, d1 = 0.f, d2 = 0.f, d3 = 0.f;
#pragma unroll
                for (int i = 0; i < 16; ++i) {
                    float4 c = ((const float4*)ckr)[i];
                    d0 = fmaf(c.x, xr[i * 4 + 0], d0);
                    d1 = fmaf(c.y, xr[i * 4 + 1], d1);
                    d2 = fmaf(c.z, xr[i * 4 + 2], d2);
                    d3 = fmaf(c.w, xr[i * 4 + 3], d3);
                }
                float dot = (d0 + d1) + (d2 + d3);
                float dist = (x_sq + csq_l[k]) - 2.0f * dot;
                if (dist < best) { best = dist; bi = k; }
            }
        }
        m_i[t] = bi;
        out[IDX_OFF + (size_t)(q0 + t) * NG + g] = (float)bi;
    }
    __syncthreads();

    // ---- epilogue: coalesced x_q writes + loss partial (r10-proven) ----
    const int r_off = t >> 4;
    const int c4i = t & 15;
    float s0 = 0.f, s1 = 0.f, s2 = 0.f, s3 = 0.f;
#pragma unroll
    for (int p = 0; p < 4; ++p) {
        const int r = p * 16 + r_off;
        const int code = m_i[r];
        const size_t base = (size_t)(q0 + r) * DIM + g * GD + c4i * 4;
        float4 x4 = *(const float4*)(x + base);
        float4 q4 = *(const float4*)(cb + ((size_t)g * NK + code) * GD + c4i * 4);
        float dx = q4.x - x4.x;
        float dy = q4.y - x4.y;
        float dz = q4.z - x4.z;
        float dw = q4.w - x4.w;
        float4 o;
        o.x = x4.x + dx;
        o.y = x4.y + dy;
        o.z = x4.z + dz;
        o.w = x4.w + dw;
        *(float4*)(out + base) = o;
        s0 = fmaf(dx, dx, s0);
        s1 = fmaf(dy, dy, s1);
        s2 = fmaf(dz, dz, s2);
        s3 = fmaf(dw, dw, s3);
    }
    float part = (s0 + s1) + (s2 + s3);
#pragma unroll
    for (int off = 32; off > 0; off >>= 1) part += __shfl_down(part, off);
    if (lane == 0) wsum[wid] = part;
    __syncthreads();
    if (t == 0) {
        float bs = (wsum[0] + wsum[1]) + (wsum[2] + wsum[3]);
        atomicAdd(out + LOSS_OFF, bs * (2.0f / 2097152.0f));
    }
}

extern "C" void kernel_launch(void* const* d_in, const int* in_sizes, int n_in,
                              void* d_out, int out_size, void* d_ws, size_t ws_size,
                              hipStream_t stream) {
    const float* x = (const float*)d_in[0];
    const float* cb = (const float*)d_in[1];
    float* out = (float*)d_out;

    pq_zero<<<dim3(1), dim3(64), 0, stream>>>(out + LOSS_OFF);

    dim3 grid(BT_TOTAL / QB, NG);   // (512, 8) = 4096 blocks
    pq_main<<<grid, dim3(256), 0, stream>>>(x, cb, out);
}

// Round 17
// 202.146 us; speedup vs baseline: 2.3814x; 1.0062x over previous
//
#include <hip/hip_runtime.h>
#include <hip/hip_bf16.h>

// Problem constants
#define BT_TOTAL (32 * 1024)   // B*T
#define DIM 512
#define NG 8
#define NK 256
#define GD 64
#define QB 64                  // queries per block (16 per wave)

#define XQ_ELEMS (BT_TOTAL * DIM)
#define LOSS_OFF XQ_ELEMS
#define IDX_OFF (XQ_ELEMS + 1)

typedef short s16x8 __attribute__((ext_vector_type(8)));
typedef float f32x4 __attribute__((ext_vector_type(4)));

__device__ __forceinline__ unsigned short f2bf(float f) {
    __hip_bfloat16 h = __float2bfloat16(f);
    union { __hip_bfloat16 h; unsigned short u; } cv;
    cv.h = h;
    return cv.u;
}

// ---------------------------------------------------------------------------
// Prep: canonical csq (bit-matches all prior rounds) + bf16 codebook (RNE,
// same convert as r16's in-block staging) into ws. One row per thread.
// ---------------------------------------------------------------------------
__global__ void pq_prep(const float* __restrict__ cb,
                        float* __restrict__ csq,
                        unsigned short* __restrict__ cbh,
                        float* __restrict__ loss_slot) {
    int i = blockIdx.x * 256 + threadIdx.x;  // 0 .. 2047
    if (i == 0) *loss_slot = 0.0f;
    if (i < NG * NK) {
        const float* row = cb + (size_t)i * GD;
        float a0 = 0.f, a1 = 0.f, a2 = 0.f, a3 = 0.f;
#pragma unroll
        for (int ii = 0; ii < 8; ++ii) {
            float4 vA = ((const float4*)row)[ii * 2 + 0];
            float4 vB = ((const float4*)row)[ii * 2 + 1];
            a0 = fmaf(vA.x, vA.x, a0); a1 = fmaf(vA.y, vA.y, a1);
            a2 = fmaf(vA.z, vA.z, a2); a3 = fmaf(vA.w, vA.w, a3);
            a0 = fmaf(vB.x, vB.x, a0); a1 = fmaf(vB.y, vB.y, a1);
            a2 = fmaf(vB.z, vB.z, a2); a3 = fmaf(vB.w, vB.w, a3);
            s16x8 w;
            w[0] = (short)f2bf(vA.x); w[1] = (short)f2bf(vA.y);
            w[2] = (short)f2bf(vA.z); w[3] = (short)f2bf(vA.w);
            w[4] = (short)f2bf(vB.x); w[5] = (short)f2bf(vB.y);
            w[6] = (short)f2bf(vB.z); w[7] = (short)f2bf(vB.w);
            *(s16x8*)&cbh[(size_t)i * GD + ii * 8] = w;
        }
        csq[i] = (a0 + a1) + (a2 + a3);
    }
}

// ---------------------------------------------------------------------------
// Main: 4 waves x 16 queries; each wave screens its queries against all 256
// codes via MFMA on precomputed bf16 codebook (global, L2-hot). Tiny LDS.
// Guaranteed-window exact fp32 rescore (r16-proven formula + numerics).
// ---------------------------------------------------------------------------
__global__ __launch_bounds__(256, 4)
void pq_main(const float* __restrict__ x,
             const float* __restrict__ cb,
             const float* __restrict__ csq_g,
             const unsigned short* __restrict__ cbh,
             float* __restrict__ out) {
    const int g = blockIdx.y;
    const int t = threadIdx.x;
    const int lane = t & 63;
    const int wm = __builtin_amdgcn_readfirstlane(t >> 6);  // wave's M tile
    const int lr = lane & 15, lh = lane >> 4;
    const int q0 = blockIdx.x * QB;

    __shared__ float csq_l[NK];        // 1024 B
    __shared__ float absrow_l[QB];
    __shared__ float sminl[QB];
    __shared__ int   swinl[QB];
    __shared__ int   ccount[QB];
    __shared__ unsigned short cand[QB][8];
    __shared__ int   m_i[QB];
    __shared__ float wsum[4];

    if (t < QB) ccount[t] = 0;
    csq_l[t] = csq_g[g * NK + t];

    // ---- A fragments direct from global x (+ row sum|x| via shuffles) ----
    const float* xbase = x + (size_t)(q0 + wm * 16 + lr) * DIM + g * GD;
    s16x8 af[2];
    float s_abs = 0.f;
#pragma unroll
    for (int s = 0; s < 2; ++s) {
        float4 vA = *(const float4*)(xbase + s * 32 + lh * 8);
        float4 vB = *(const float4*)(xbase + s * 32 + lh * 8 + 4);
        s_abs += fabsf(vA.x) + fabsf(vA.y) + fabsf(vA.z) + fabsf(vA.w)
               + fabsf(vB.x) + fabsf(vB.y) + fabsf(vB.z) + fabsf(vB.w);
        s16x8 w;
        w[0] = (short)f2bf(vA.x); w[1] = (short)f2bf(vA.y);
        w[2] = (short)f2bf(vA.z); w[3] = (short)f2bf(vA.w);
        w[4] = (short)f2bf(vB.x); w[5] = (short)f2bf(vB.y);
        w[6] = (short)f2bf(vB.z); w[7] = (short)f2bf(vB.w);
        af[s] = w;
    }
    s_abs += __shfl_xor(s_abs, 16);
    s_abs += __shfl_xor(s_abs, 32);
    if (lh == 0) absrow_l[wm * 16 + lr] = s_abs;
    __syncthreads();   // csq_l ready (absrow/sminl are intra-wave + later sync)

    // ---- MFMA screen: 16 N tiles x (K=64 -> 2 MFMAs) ----
    const unsigned short* cbase = cbh + (size_t)g * NK * GD;
    f32x4 acc[16];
#pragma unroll
    for (int n = 0; n < 16; ++n) {
        s16x8 b0 = *(const s16x8*)&cbase[(n * 16 + lr) * GD + lh * 8];
        s16x8 b1 = *(const s16x8*)&cbase[(n * 16 + lr) * GD + 32 + lh * 8];
        f32x4 z = {0.f, 0.f, 0.f, 0.f};
        z = __builtin_amdgcn_mfma_f32_16x16x32_bf16(af[0], b0, z, 0, 0, 0);
        z = __builtin_amdgcn_mfma_f32_16x16x32_bf16(af[1], b1, z, 0, 0, 0);
        acc[n] = z;
    }

    // ---- per-lane fold (k ascending) + 16-lane lexicographic reduce ----
    float mv[4]; int mi[4];
#pragma unroll
    for (int r = 0; r < 4; ++r) { mv[r] = 3.402823466e38f; mi[r] = 0; }
#pragma unroll
    for (int n = 0; n < 16; ++n) {
        const float cs = csq_l[n * 16 + lr];
        const int k = n * 16 + lr;
#pragma unroll
        for (int r = 0; r < 4; ++r) {
            float dc = fmaf(-2.f, acc[n][r], cs);
            if (dc < mv[r]) { mv[r] = dc; mi[r] = k; }
        }
    }
#pragma unroll
    for (int w = 1; w < 16; w <<= 1) {
#pragma unroll
        for (int r = 0; r < 4; ++r) {
            float ov = __shfl_xor(mv[r], w);
            int   oi = __shfl_xor(mi[r], w);
            if (ov < mv[r] || (ov == mv[r] && oi < mi[r])) { mv[r] = ov; mi[r] = oi; }
        }
    }
    if (lr == 0) {
#pragma unroll
        for (int r = 0; r < 4; ++r) {
            sminl[wm * 16 + lh * 4 + r] = mv[r];
            swinl[wm * 16 + lh * 4 + r] = mi[r];
        }
    }
    __syncthreads();

    // ---- flag candidates in the guaranteed window (r16-proven formula) ----
#pragma unroll
    for (int r = 0; r < 4; ++r) {
        const int row = wm * 16 + lh * 4 + r;
        const float thr = sminl[row] + (absrow_l[row] * 6.2e-5f + 1.5e-3f);
#pragma unroll
        for (int n = 0; n < 16; ++n) {
            float dc = fmaf(-2.f, acc[n][r], csq_l[n * 16 + lr]);
            if (dc <= thr) {
                int slot = atomicAdd(&ccount[row], 1);
                if (slot < 8) cand[row][slot] = (unsigned short)(n * 16 + lr);
            }
        }
    }
    __syncthreads();

    // ---- exact fp32 rescore (canonical absmax-0.0 numerics, r16 verbatim) ----
    if (t < QB) {
        const int nc = ccount[t];
        int bi;
        if (nc <= 1) {
            bi = swinl[t];
        } else {
            const float* xrow = x + (size_t)(q0 + t) * DIM + g * GD;
            float xr[64];
#pragma unroll
            for (int i = 0; i < 16; ++i) {
                float4 v = ((const float4*)xrow)[i];
                xr[i * 4 + 0] = v.x; xr[i * 4 + 1] = v.y;
                xr[i * 4 + 2] = v.z; xr[i * 4 + 3] = v.w;
            }
            float a0 = 0.f, a1 = 0.f, a2 = 0.f, a3 = 0.f;
#pragma unroll
            for (int i = 0; i < 16; ++i) {
                a0 = fmaf(xr[i * 4 + 0], xr[i * 4 + 0], a0);
                a1 = fmaf(xr[i * 4 + 1], xr[i * 4 + 1], a1);
                a2 = fmaf(xr[i * 4 + 2], xr[i * 4 + 2], a2);
                a3 = fmaf(xr[i * 4 + 3], xr[i * 4 + 3], a3);
            }
            const float x_sq = (a0 + a1) + (a2 + a3);

            const bool full = nc > 8;   // astronomically rare; exact fallback
            unsigned short ks[8];
            const int mcnt = full ? 0 : nc;
            for (int i = 0; i < mcnt; ++i) ks[i] = cand[t][i];
            for (int i = 1; i < mcnt; ++i) {
                unsigned short key = ks[i];
                int j = i - 1;
                while (j >= 0 && ks[j] > key) { ks[j + 1] = ks[j]; --j; }
                ks[j + 1] = key;
            }
            float best = 3.402823466e38f; bi = 0;
            const int total = full ? NK : mcnt;
            for (int ii = 0; ii < total; ++ii) {
                const int k = full ? ii : (int)ks[ii];
                const float* ckr = cb + ((size_t)g * NK + k) * GD;
                float d0 = 0.f, d1 = 0.f, d2 = 0.f, d3 = 0.f;
#pragma unroll
                for (int i = 0; i < 16; ++i) {
                    float4 c = ((const float4*)ckr)[i];
                    d0 = fmaf(c.x, xr[i * 4 + 0], d0);
                    d1 = fmaf(c.y, xr[i * 4 + 1], d1);
                    d2 = fmaf(c.z, xr[i * 4 + 2], d2);
                    d3 = fmaf(c.w, xr[i * 4 + 3], d3);
                }
                float dot = (d0 + d1) + (d2 + d3);
                float dist = (x_sq + csq_l[k]) - 2.0f * dot;
                if (dist < best) { best = dist; bi = k; }
            }
        }
        m_i[t] = bi;
        out[IDX_OFF + (size_t)(q0 + t) * NG + g] = (float)bi;
    }
    __syncthreads();

    // ---- epilogue: coalesced x_q writes + loss partial (proven) ----
    const int r_off = t >> 4;
    const int c4i = t & 15;
    float s0 = 0.f, s1 = 0.f, s2 = 0.f, s3 = 0.f;
#pragma unroll
    for (int p = 0; p < 4; ++p) {
        const int r = p * 16 + r_off;
        const int code = m_i[r];
        const size_t base = (size_t)(q0 + r) * DIM + g * GD + c4i * 4;
        float4 x4 = *(const float4*)(x + base);
        float4 q4 = *(const float4*)(cb + ((size_t)g * NK + code) * GD + c4i * 4);
        float dx = q4.x - x4.x;
        float dy = q4.y - x4.y;
        float dz = q4.z - x4.z;
        float dw = q4.w - x4.w;
        float4 o;
        o.x = x4.x + dx;
        o.y = x4.y + dy;
        o.z = x4.z + dz;
        o.w = x4.w + dw;
        *(float4*)(out + base) = o;
        s0 = fmaf(dx, dx, s0);
        s1 = fmaf(dy, dy, s1);
        s2 = fmaf(dz, dz, s2);
        s3 = fmaf(dw, dw, s3);
    }
    float part = (s0 + s1) + (s2 + s3);
#pragma unroll
    for (int off = 32; off > 0; off >>= 1) part += __shfl_down(part, off);
    if (lane == 0) wsum[wm] = part;
    __syncthreads();
    if (t == 0) {
        float bs = (wsum[0] + wsum[1]) + (wsum[2] + wsum[3]);
        atomicAdd(out + LOSS_OFF, bs * (2.0f / 2097152.0f));
    }
}

extern "C" void kernel_launch(void* const* d_in, const int* in_sizes, int n_in,
                              void* d_out, int out_size, void* d_ws, size_t ws_size,
                              hipStream_t stream) {
    const float* x = (const float*)d_in[0];
    const float* cb = (const float*)d_in[1];
    float* out = (float*)d_out;
    float* csq = (float*)d_ws;                              // 8 KB
    unsigned short* cbh = (unsigned short*)(csq + NG * NK); // 256 KB bf16 codebook

    pq_prep<<<dim3(8), dim3(256), 0, stream>>>(cb, csq, cbh, out + LOSS_OFF);

    dim3 grid(BT_TOTAL / QB, NG);   // (512, 8) = 4096 blocks
    pq_main<<<grid, dim3(256), 0, stream>>>(x, cb, csq, cbh, out);
}